// Round 14
// baseline (707.850 us; speedup 1.0000x reference)
//
#include <hip/hip_runtime.h>
#include <hip/hip_bf16.h>

#define S_LEN 2048
#define BATCH 2
#define DIM 128
#define NH 8
#define HD 1024
#define QL 5
#define KKTOT 640   // DIM*QL
#define OCH 2048
#define MAXNNZ 384

// ---------------- transpose w_qk (O,I,T) -> (I*T, O) for coalesced GEMM reads
__global__ void k_transpose_wqk(const float* __restrict__ w, float* __restrict__ wt) {
    int i = blockIdx.x * 256 + threadIdx.x;   // i = kk*2048 + o
    if (i >= KKTOT * OCH) return;
    int kk = i >> 11;
    int o  = i & 2047;
    wt[i] = w[o * KKTOT + kk];
}

// ---------------- compact mask rows to CSR (deterministic ballot compaction)
__global__ void k_mask_csr(const float* __restrict__ mask, unsigned* __restrict__ cnt,
                           unsigned* __restrict__ idx) {
    __shared__ unsigned s_base;
    __shared__ unsigned s_wcnt[4];
    int r = blockIdx.x;
    int tid = threadIdx.x;
    int lane = tid & 63;
    int w = tid >> 6;
    if (tid == 0) s_base = 0;
    __syncthreads();
    for (int c0 = 0; c0 < S_LEN; c0 += 256) {
        int c = c0 + tid;
        bool act = mask[(size_t)r * S_LEN + c] > 0.5f;
        unsigned long long bal = __ballot(act);
        if (lane == 0) s_wcnt[w] = (unsigned)__popcll(bal);
        __syncthreads();
        unsigned off = s_base;
        for (int i = 0; i < w; i++) off += s_wcnt[i];
        off += (unsigned)__popcll(bal & ((1ull << lane) - 1ull));
        if (act && off < MAXNNZ) idx[r * MAXNNZ + off] = (unsigned)c;
        __syncthreads();
        if (tid == 0) s_base += s_wcnt[0] + s_wcnt[1] + s_wcnt[2] + s_wcnt[3];
        __syncthreads();
    }
    if (tid == 0) cnt[r] = (s_base < MAXNNZ) ? s_base : MAXNNZ;
}

// ---------------- value = x @ w_v + b_v   (B*S,128)x(128,1024)
// grid (BATCH*S/16, 4), block 256
__global__ void k_value(const float* __restrict__ x, const float* __restrict__ wv,
                        const float* __restrict__ bv, float* __restrict__ val) {
    __shared__ float xs[16][128];
    int bs0 = blockIdx.x * 16;
    int c = blockIdx.y * 256 + threadIdx.x;
    for (int t = threadIdx.x; t < 16 * 128; t += 256)
        xs[t >> 7][t & 127] = x[(size_t)(bs0 + (t >> 7)) * DIM + (t & 127)];
    __syncthreads();
    float acc[16];
#pragma unroll
    for (int r = 0; r < 16; r++) acc[r] = 0.f;
    for (int k = 0; k < 128; k += 4) {
        float w0 = wv[(k + 0) * HD + c];
        float w1 = wv[(k + 1) * HD + c];
        float w2 = wv[(k + 2) * HD + c];
        float w3 = wv[(k + 3) * HD + c];
#pragma unroll
        for (int r = 0; r < 16; r++) {
            float4 xv = *reinterpret_cast<const float4*>(&xs[r][k]);
            acc[r] += xv.x * w0 + xv.y * w1 + xv.z * w2 + xv.w * w3;
        }
    }
    float b = bv[c];
#pragma unroll
    for (int r = 0; r < 16; r++)
        val[(size_t)(bs0 + r) * HD + c] = acc[r] + b;
}

// ---------------- qk = causal_conv(x, w_qk) + b_qk  as GEMM with K=640
// grid (BATCH*S/32, 8), block 256
__global__ void k_qkconv(const float* __restrict__ x, const float* __restrict__ wt,
                         const float* __restrict__ bqk, float* __restrict__ qk) {
    __shared__ float xs[36][128];
    int bs0 = blockIdx.x * 32;
    int b = bs0 >> 11;
    int s0 = bs0 & 2047;
    int o = blockIdx.y * 256 + threadIdx.x;
    for (int t = threadIdx.x; t < 36 * 128; t += 256) {
        int rr = t >> 7, i = t & 127;
        int s = s0 - 4 + rr;
        float v = 0.f;
        if (s >= 0) v = x[((size_t)b * S_LEN + s) * DIM + i];
        xs[rr][i] = v;
    }
    __syncthreads();
    float acc[32];
    float bias = bqk[o];
#pragma unroll
    for (int r = 0; r < 32; r++) acc[r] = bias;
    for (int i = 0; i < 128; i += 2) {
        float2 xr[36];
#pragma unroll
        for (int rr = 0; rr < 36; rr++)
            xr[rr] = *reinterpret_cast<const float2*>(&xs[rr][i]);
#pragma unroll
        for (int t = 0; t < QL; t++) {
            float wA = wt[((i + 0) * QL + t) * OCH + o];
            float wB = wt[((i + 1) * QL + t) * OCH + o];
#pragma unroll
            for (int r = 0; r < 32; r++)
                acc[r] += xr[r + t].x * wA + xr[r + t].y * wB;
        }
    }
    for (int r = 0; r < 32; r++)
        qk[((size_t)bs0 + r) * OCH + o] = acc[r];
}

// ---------------- sparse attention + entmax15
// QK: 4-lane groups, 2-col unroll; entmax tau: all-wave redundant Newton;
// PV: 8 col-slots x 32 float4 dims.
__global__ void __launch_bounds__(256) k_attn(const float* __restrict__ qk,
                                              const float* __restrict__ val,
                                              const unsigned* __restrict__ cnt,
                                              const unsigned* __restrict__ idxbuf,
                                              float* __restrict__ attout) {
    __shared__ float qs[128];
    __shared__ float ssc[MAXNNZ];
    __shared__ unsigned sidx[MAXNNZ];
    __shared__ float4 pv4[8][32];
    int bid = blockIdx.x;
    int r = bid & (S_LEN - 1);
    int h = (bid >> 11) & (NH - 1);
    int b = bid >> 14;
    int tid = threadIdx.x;
    int lane = tid & 63;
    int wave = tid >> 6;
    int n = (int)cnt[r];
    const float scale = 0.08838834764831843f;  // 1/sqrt(128)

    if (tid < 128) qs[tid] = qk[((size_t)(b * S_LEN + r)) * OCH + h * 128 + tid];
    for (int j = tid; j < n; j += 256) sidx[j] = idxbuf[r * MAXNNZ + j];
    __syncthreads();

    // ---- phase 1: scores, 2 columns per 4-lane group iteration (ILP)
    {
        int grp = tid >> 2;          // 0..63
        int ll  = tid & 3;           // lane within group
        const float* kbase = qk + (size_t)b * S_LEN * OCH + HD + h * 128;
        for (int j0 = grp; j0 < n; j0 += 128) {
            int j1 = j0 + 64;
            bool has1 = j1 < n;
            const float* kp0 = kbase + ((size_t)sidx[j0]) * OCH;
            const float* kp1 = has1 ? kbase + ((size_t)sidx[j1]) * OCH : kp0;
            float p0 = 0.f, p1 = 0.f;
#pragma unroll
            for (int i = 0; i < 8; i++) {
                int m = (i * 4 + ll) << 2;                 // float offset
                float4 qv = *reinterpret_cast<const float4*>(&qs[m]);
                float4 k0 = *reinterpret_cast<const float4*>(kp0 + m);
                float4 k1 = *reinterpret_cast<const float4*>(kp1 + m);
                p0 += qv.x * k0.x + qv.y * k0.y + qv.z * k0.z + qv.w * k0.w;
                p1 += qv.x * k1.x + qv.y * k1.y + qv.z * k1.z + qv.w * k1.w;
            }
            p0 += __shfl_xor(p0, 1, 64);
            p0 += __shfl_xor(p0, 2, 64);
            p1 += __shfl_xor(p1, 1, 64);
            p1 += __shfl_xor(p1, 2, 64);
            if (ll == 0) {
                ssc[j0] = p0 * scale;
                if (has1) ssc[j1] = p1 * scale;
            }
        }
    }
    __syncthreads();

    // ---- phase 2: entmax tau via all-wave redundant Newton (unshifted)
    // f(tau) = sum((x - tau)_+^2), x = score/2; root in [xmax-1, xmax).
    // Newton from below: monotone, no overshoot (f convex decreasing, s1 >= 1).
    {
        int nl = (n + 63) >> 6;      // 1..6 slices
        float xl[6];
        float mx = -3.0e38f;
        for (int l = 0; l < nl; l++) {
            int j = lane + (l << 6);
            xl[l] = (j < n) ? ssc[j] * 0.5f : -3.0e38f;
            mx = fmaxf(mx, xl[l]);
        }
#pragma unroll
        for (int off = 32; off >= 1; off >>= 1) mx = fmaxf(mx, __shfl_xor(mx, off, 64));
        __syncthreads();             // all waves done READING ssc before weights overwrite it
        float tau = mx - 1.f;
        for (int it = 0; it < 12; it++) {
            float s1 = 0.f, s2 = 0.f;
            for (int l = 0; l < nl; l++) {
                float d = fmaxf(xl[l] - tau, 0.f);
                s1 += d;
                s2 += d * d;
            }
#pragma unroll
            for (int off = 32; off >= 1; off >>= 1) {
                s1 += __shfl_xor(s1, off, 64);
                s2 += __shfl_xor(s2, off, 64);
            }
            tau += (s2 - 1.f) / (2.f * s1);
        }
        // write weights: wave w owns slices l with (l & 3) == w
        for (int l = 0; l < nl; l++) {
            if ((l & 3) == wave) {
                int j = lane + (l << 6);
                if (j < n) {
                    float d = fmaxf(xl[l] - tau, 0.f);
                    ssc[j] = d * d;
                }
            }
        }
    }
    __syncthreads();

    // ---- phase 3: PV, vectorized — 8 column-slots x 32 float4 dim-groups
    {
        int slot = tid >> 5;         // 0..7
        int dg   = tid & 31;         // float4 dim group 0..31
        const float4* vbase = reinterpret_cast<const float4*>(
                                  val + (size_t)b * S_LEN * HD + h * 128) + dg;
        float4 acc = {0.f, 0.f, 0.f, 0.f};
        for (int j = slot; j < n; j += 8) {
            float w = ssc[j];
            float4 v = vbase[(size_t)sidx[j] << 8];     // c * HD/4 float4s
            acc.x += w * v.x; acc.y += w * v.y; acc.z += w * v.z; acc.w += w * v.w;
        }
        pv4[slot][dg] = acc;
    }
    __syncthreads();
    if (tid < 128) {
        int d4 = tid >> 2, comp = tid & 3;
        float a = 0.f;
#pragma unroll
        for (int s = 0; s < 8; s++) a += reinterpret_cast<const float*>(&pv4[s][d4])[comp];
        attout[((size_t)(b * S_LEN + r)) * HD + h * 128 + tid] = a;
    }
}

// ---------------- out = attout @ w_proj + b_proj, store FLOAT32
// grid BATCH*S/16, block 256 (2-way split-K x 128 cols)
__global__ void k_proj(const float* __restrict__ ao, const float* __restrict__ wp,
                       const float* __restrict__ bp, float* __restrict__ out) {
    __shared__ float xs[2][16][128];
    int bs0 = blockIdx.x * 16;
    int tid = threadIdx.x;
    int dout = tid & 127;
    int kh = tid >> 7;
    float acc[16];
#pragma unroll
    for (int r = 0; r < 16; r++) acc[r] = 0.f;
    for (int cc = 0; cc < 4; cc++) {
        int kb = (kh + 2 * cc) * 128;
        __syncthreads();
        for (int t = dout; t < 16 * 128; t += 128)
            xs[kh][t >> 7][t & 127] = ao[(size_t)(bs0 + (t >> 7)) * HD + kb + (t & 127)];
        __syncthreads();
        for (int k = 0; k < 128; k += 4) {
            float w0 = wp[(kb + k + 0) * DIM + dout];
            float w1 = wp[(kb + k + 1) * DIM + dout];
            float w2 = wp[(kb + k + 2) * DIM + dout];
            float w3 = wp[(kb + k + 3) * DIM + dout];
#pragma unroll
            for (int r = 0; r < 16; r++) {
                float4 xv = *reinterpret_cast<const float4*>(&xs[kh][r][k]);
                acc[r] += xv.x * w0 + xv.y * w1 + xv.z * w2 + xv.w * w3;
            }
        }
    }
    __syncthreads();
#pragma unroll
    for (int r = 0; r < 16; r++) xs[kh][r][dout] = acc[r];
    __syncthreads();
    if (kh == 0) {
        float bb = bp[dout];
        for (int r = 0; r < 16; r++)
            out[(size_t)(bs0 + r) * DIM + dout] = xs[0][r][dout] + xs[1][r][dout] + bb;
    }
}

extern "C" void kernel_launch(void* const* d_in, const int* in_sizes, int n_in,
                              void* d_out, int out_size, void* d_ws, size_t ws_size,
                              hipStream_t stream) {
    const float* x      = (const float*)d_in[0];
    const float* mask   = (const float*)d_in[1];
    const float* w_qk   = (const float*)d_in[2];
    const float* b_qk   = (const float*)d_in[3];
    const float* w_v    = (const float*)d_in[4];
    const float* b_v    = (const float*)d_in[5];
    const float* w_proj = (const float*)d_in[6];
    const float* b_proj = (const float*)d_in[7];
    float* out = (float*)d_out;     // reference output dtype is FLOAT32

    // tight workspace packing (total 75,505,664 B ~ 72 MiB)
    char* ws = (char*)d_ws;
    float*    val  = (float*)(ws + 0);           // 16,777,216 B
    float*    qk   = (float*)(ws + 16777216);    // 33,554,432 B
    float*    wt   = (float*)(ws + 50331648);    //  5,242,880 B
    unsigned* cnt  = (unsigned*)(ws + 55574528); //      8,192 B
    unsigned* idx  = (unsigned*)(ws + 55582720); //  3,145,728 B
    float*    ao   = (float*)(ws + 58728448);    // 16,777,216 B -> end 75,505,664

    hipLaunchKernelGGL(k_transpose_wqk, dim3((KKTOT * OCH) / 256), dim3(256), 0, stream, w_qk, wt);
    hipLaunchKernelGGL(k_mask_csr, dim3(S_LEN), dim3(256), 0, stream, mask, cnt, idx);
    hipLaunchKernelGGL(k_value, dim3((BATCH * S_LEN) / 16, 4), dim3(256), 0, stream, x, w_v, b_v, val);
    hipLaunchKernelGGL(k_qkconv, dim3((BATCH * S_LEN) / 32, 8), dim3(256), 0, stream, x, wt, b_qk, qk);
    hipLaunchKernelGGL(k_attn, dim3(BATCH * NH * S_LEN), dim3(256), 0, stream, qk, val, cnt, idx, ao);
    hipLaunchKernelGGL(k_proj, dim3((BATCH * S_LEN) / 16), dim3(256), 0, stream, ao, w_proj, b_proj, out);
}

// Round 15
// 672.184 us; speedup vs baseline: 1.0531x; 1.0531x over previous
//
#include <hip/hip_runtime.h>
#include <hip/hip_bf16.h>

#define S_LEN 2048
#define BATCH 2
#define DIM 128
#define NH 8
#define HD 1024
#define QL 5
#define KKTOT 640   // DIM*QL
#define OCH 2048
#define MAXNNZ 384

// ---------------- transpose w_qk (O,I,T) -> (I*T, O) for coalesced GEMM reads
__global__ void k_transpose_wqk(const float* __restrict__ w, float* __restrict__ wt) {
    int i = blockIdx.x * 256 + threadIdx.x;   // i = kk*2048 + o
    if (i >= KKTOT * OCH) return;
    int kk = i >> 11;
    int o  = i & 2047;
    wt[i] = w[o * KKTOT + kk];
}

// ---------------- compact mask rows to CSR (deterministic ballot compaction)
__global__ void k_mask_csr(const float* __restrict__ mask, unsigned* __restrict__ cnt,
                           unsigned* __restrict__ idx) {
    __shared__ unsigned s_base;
    __shared__ unsigned s_wcnt[4];
    int r = blockIdx.x;
    int tid = threadIdx.x;
    int lane = tid & 63;
    int w = tid >> 6;
    if (tid == 0) s_base = 0;
    __syncthreads();
    for (int c0 = 0; c0 < S_LEN; c0 += 256) {
        int c = c0 + tid;
        bool act = mask[(size_t)r * S_LEN + c] > 0.5f;
        unsigned long long bal = __ballot(act);
        if (lane == 0) s_wcnt[w] = (unsigned)__popcll(bal);
        __syncthreads();
        unsigned off = s_base;
        for (int i = 0; i < w; i++) off += s_wcnt[i];
        off += (unsigned)__popcll(bal & ((1ull << lane) - 1ull));
        if (act && off < MAXNNZ) idx[r * MAXNNZ + off] = (unsigned)c;
        __syncthreads();
        if (tid == 0) s_base += s_wcnt[0] + s_wcnt[1] + s_wcnt[2] + s_wcnt[3];
        __syncthreads();
    }
    if (tid == 0) cnt[r] = (s_base < MAXNNZ) ? s_base : MAXNNZ;
}

// ---------------- value = x @ w_v + b_v   (B*S,128)x(128,1024)
// grid (BATCH*S/16, 4), block 256
__global__ void k_value(const float* __restrict__ x, const float* __restrict__ wv,
                        const float* __restrict__ bv, float* __restrict__ val) {
    __shared__ float xs[16][128];
    int bs0 = blockIdx.x * 16;
    int c = blockIdx.y * 256 + threadIdx.x;
    for (int t = threadIdx.x; t < 16 * 128; t += 256)
        xs[t >> 7][t & 127] = x[(size_t)(bs0 + (t >> 7)) * DIM + (t & 127)];
    __syncthreads();
    float acc[16];
#pragma unroll
    for (int r = 0; r < 16; r++) acc[r] = 0.f;
    for (int k = 0; k < 128; k += 4) {
        float w0 = wv[(k + 0) * HD + c];
        float w1 = wv[(k + 1) * HD + c];
        float w2 = wv[(k + 2) * HD + c];
        float w3 = wv[(k + 3) * HD + c];
#pragma unroll
        for (int r = 0; r < 16; r++) {
            float4 xv = *reinterpret_cast<const float4*>(&xs[r][k]);
            acc[r] += xv.x * w0 + xv.y * w1 + xv.z * w2 + xv.w * w3;
        }
    }
    float b = bv[c];
#pragma unroll
    for (int r = 0; r < 16; r++)
        val[(size_t)(bs0 + r) * HD + c] = acc[r] + b;
}

// ---------------- qk = causal_conv(x, w_qk) + b_qk  as GEMM with K=640
// grid (BATCH*S/32, 8), block 256
__global__ void k_qkconv(const float* __restrict__ x, const float* __restrict__ wt,
                         const float* __restrict__ bqk, float* __restrict__ qk) {
    __shared__ float xs[36][128];
    int bs0 = blockIdx.x * 32;
    int b = bs0 >> 11;
    int s0 = bs0 & 2047;
    int o = blockIdx.y * 256 + threadIdx.x;
    for (int t = threadIdx.x; t < 36 * 128; t += 256) {
        int rr = t >> 7, i = t & 127;
        int s = s0 - 4 + rr;
        float v = 0.f;
        if (s >= 0) v = x[((size_t)b * S_LEN + s) * DIM + i];
        xs[rr][i] = v;
    }
    __syncthreads();
    float acc[32];
    float bias = bqk[o];
#pragma unroll
    for (int r = 0; r < 32; r++) acc[r] = bias;
    for (int i = 0; i < 128; i += 2) {
        float2 xr[36];
#pragma unroll
        for (int rr = 0; rr < 36; rr++)
            xr[rr] = *reinterpret_cast<const float2*>(&xs[rr][i]);
#pragma unroll
        for (int t = 0; t < QL; t++) {
            float wA = wt[((i + 0) * QL + t) * OCH + o];
            float wB = wt[((i + 1) * QL + t) * OCH + o];
#pragma unroll
            for (int r = 0; r < 32; r++)
                acc[r] += xr[r + t].x * wA + xr[r + t].y * wB;
        }
    }
    for (int r = 0; r < 32; r++)
        qk[((size_t)bs0 + r) * OCH + o] = acc[r];
}

// ---------------- sparse attention + entmax15
// QK: 4-lane groups, 2-col unroll; tau: wave-0 bisection (r13); PV: 2-slot unroll.
__global__ void __launch_bounds__(256) k_attn(const float* __restrict__ qk,
                                              const float* __restrict__ val,
                                              const unsigned* __restrict__ cnt,
                                              const unsigned* __restrict__ idxbuf,
                                              float* __restrict__ attout) {
    __shared__ float qs[128];
    __shared__ float ssc[MAXNNZ];
    __shared__ unsigned sidx[MAXNNZ];
    __shared__ float4 pv4[8][32];
    __shared__ float red4[4];
    __shared__ float s_mx;
    int bid = blockIdx.x;
    int r = bid & (S_LEN - 1);
    int h = (bid >> 11) & (NH - 1);
    int b = bid >> 14;
    int tid = threadIdx.x;
    int lane = tid & 63;
    int wave = tid >> 6;
    int n = (int)cnt[r];
    const float scale = 0.08838834764831843f;  // 1/sqrt(128)

    if (tid < 128) qs[tid] = qk[((size_t)(b * S_LEN + r)) * OCH + h * 128 + tid];
    for (int j = tid; j < n; j += 256) sidx[j] = idxbuf[r * MAXNNZ + j];
    __syncthreads();

    // ---- phase 1: scores, 2 columns per 4-lane group iteration (MLP)
    {
        int grp = tid >> 2;          // 0..63
        int ll  = tid & 3;           // lane within group
        const float* kbase = qk + (size_t)b * S_LEN * OCH + HD + h * 128;
        for (int j0 = grp; j0 < n; j0 += 128) {
            int j1 = j0 + 64;
            bool has1 = j1 < n;
            const float* kp0 = kbase + ((size_t)sidx[j0]) * OCH;
            const float* kp1 = has1 ? kbase + ((size_t)sidx[j1]) * OCH : kp0;
            float p0 = 0.f, p1 = 0.f;
#pragma unroll
            for (int i = 0; i < 8; i++) {
                int m = (i * 4 + ll) << 2;                 // float offset
                float4 qv = *reinterpret_cast<const float4*>(&qs[m]);
                float4 k0 = *reinterpret_cast<const float4*>(kp0 + m);
                float4 k1 = *reinterpret_cast<const float4*>(kp1 + m);
                p0 += qv.x * k0.x + qv.y * k0.y + qv.z * k0.z + qv.w * k0.w;
                p1 += qv.x * k1.x + qv.y * k1.y + qv.z * k1.z + qv.w * k1.w;
            }
            p0 += __shfl_xor(p0, 1, 64);
            p0 += __shfl_xor(p0, 2, 64);
            p1 += __shfl_xor(p1, 1, 64);
            p1 += __shfl_xor(p1, 2, 64);
            if (ll == 0) {
                ssc[j0] = p0 * scale;
                if (has1) ssc[j1] = p1 * scale;
            }
        }
    }
    __syncthreads();

    // ---- phase 2a: block-wide max (r13)
    {
        float lmx = -3.0e38f;
        for (int j = tid; j < n; j += 256) lmx = fmaxf(lmx, ssc[j]);
#pragma unroll
        for (int off = 32; off >= 1; off >>= 1) lmx = fmaxf(lmx, __shfl_xor(lmx, off, 64));
        if (lane == 0) red4[wave] = lmx;
    }
    __syncthreads();
    if (tid == 0) s_mx = fmaxf(fmaxf(red4[0], red4[1]), fmaxf(red4[2], red4[3]));
    __syncthreads();
    float mx = s_mx;

    // ---- phase 2b: bisection on wave 0 (r13: tree-summed, 26 iters)
    if (wave == 0) {
        float xl[6];
#pragma unroll
        for (int l = 0; l < 6; l++) {
            int j = lane + 64 * l;
            xl[l] = (j < n) ? (ssc[j] - mx) * 0.5f : -1.0e30f;
        }
        float lo = -1.f, hi = 0.f;
        for (int it = 0; it < 26; it++) {
            float mid = 0.5f * (lo + hi);
            float d0 = fmaxf(xl[0] - mid, 0.f), d1 = fmaxf(xl[1] - mid, 0.f);
            float d2 = fmaxf(xl[2] - mid, 0.f), d3 = fmaxf(xl[3] - mid, 0.f);
            float d4 = fmaxf(xl[4] - mid, 0.f), d5 = fmaxf(xl[5] - mid, 0.f);
            float f = ((d0 * d0 + d1 * d1) + (d2 * d2 + d3 * d3)) + (d4 * d4 + d5 * d5);
#pragma unroll
            for (int off = 32; off >= 1; off >>= 1) f += __shfl_xor(f, off, 64);
            if (f > 1.f) lo = mid; else hi = mid;
        }
        float tau = 0.5f * (lo + hi);
#pragma unroll
        for (int l = 0; l < 6; l++) {
            int j = lane + 64 * l;
            if (j < n) {
                float d = fmaxf(xl[l] - tau, 0.f);
                ssc[j] = d * d;
            }
        }
    }
    __syncthreads();

    // ---- phase 3: PV, 2 slots per iteration, dual accumulators (MLP)
    {
        int slot = tid >> 5;         // 0..7
        int dg   = tid & 31;         // float4 dim group 0..31
        const float4* vbase = reinterpret_cast<const float4*>(
                                  val + (size_t)b * S_LEN * HD + h * 128) + dg;
        float4 accA = {0.f, 0.f, 0.f, 0.f};
        float4 accB = {0.f, 0.f, 0.f, 0.f};
        int j = slot;
        for (; j + 8 < n; j += 16) {
            float wA = ssc[j];
            float wB = ssc[j + 8];
            float4 vA = vbase[(size_t)sidx[j] << 8];
            float4 vB = vbase[(size_t)sidx[j + 8] << 8];
            accA.x += wA * vA.x; accA.y += wA * vA.y; accA.z += wA * vA.z; accA.w += wA * vA.w;
            accB.x += wB * vB.x; accB.y += wB * vB.y; accB.z += wB * vB.z; accB.w += wB * vB.w;
        }
        if (j < n) {
            float wA = ssc[j];
            float4 vA = vbase[(size_t)sidx[j] << 8];
            accA.x += wA * vA.x; accA.y += wA * vA.y; accA.z += wA * vA.z; accA.w += wA * vA.w;
        }
        accA.x += accB.x; accA.y += accB.y; accA.z += accB.z; accA.w += accB.w;
        pv4[slot][dg] = accA;
    }
    __syncthreads();
    if (tid < 128) {
        int d4 = tid >> 2, comp = tid & 3;
        float a = 0.f;
#pragma unroll
        for (int s = 0; s < 8; s++) a += reinterpret_cast<const float*>(&pv4[s][d4])[comp];
        attout[((size_t)(b * S_LEN + r)) * HD + h * 128 + tid] = a;
    }
}

// ---------------- out = attout @ w_proj + b_proj, store FLOAT32
// grid BATCH*S/16, block 256 (2-way split-K x 128 cols)
__global__ void k_proj(const float* __restrict__ ao, const float* __restrict__ wp,
                       const float* __restrict__ bp, float* __restrict__ out) {
    __shared__ float xs[2][16][128];
    int bs0 = blockIdx.x * 16;
    int tid = threadIdx.x;
    int dout = tid & 127;
    int kh = tid >> 7;
    float acc[16];
#pragma unroll
    for (int r = 0; r < 16; r++) acc[r] = 0.f;
    for (int cc = 0; cc < 4; cc++) {
        int kb = (kh + 2 * cc) * 128;
        __syncthreads();
        for (int t = dout; t < 16 * 128; t += 128)
            xs[kh][t >> 7][t & 127] = ao[(size_t)(bs0 + (t >> 7)) * HD + kb + (t & 127)];
        __syncthreads();
        for (int k = 0; k < 128; k += 4) {
            float w0 = wp[(kb + k + 0) * DIM + dout];
            float w1 = wp[(kb + k + 1) * DIM + dout];
            float w2 = wp[(kb + k + 2) * DIM + dout];
            float w3 = wp[(kb + k + 3) * DIM + dout];
#pragma unroll
            for (int r = 0; r < 16; r++) {
                float4 xv = *reinterpret_cast<const float4*>(&xs[kh][r][k]);
                acc[r] += xv.x * w0 + xv.y * w1 + xv.z * w2 + xv.w * w3;
            }
        }
    }
    __syncthreads();
#pragma unroll
    for (int r = 0; r < 16; r++) xs[kh][r][dout] = acc[r];
    __syncthreads();
    if (kh == 0) {
        float bb = bp[dout];
        for (int r = 0; r < 16; r++)
            out[(size_t)(bs0 + r) * DIM + dout] = xs[0][r][dout] + xs[1][r][dout] + bb;
    }
}

extern "C" void kernel_launch(void* const* d_in, const int* in_sizes, int n_in,
                              void* d_out, int out_size, void* d_ws, size_t ws_size,
                              hipStream_t stream) {
    const float* x      = (const float*)d_in[0];
    const float* mask   = (const float*)d_in[1];
    const float* w_qk   = (const float*)d_in[2];
    const float* b_qk   = (const float*)d_in[3];
    const float* w_v    = (const float*)d_in[4];
    const float* b_v    = (const float*)d_in[5];
    const float* w_proj = (const float*)d_in[6];
    const float* b_proj = (const float*)d_in[7];
    float* out = (float*)d_out;     // reference output dtype is FLOAT32

    // tight workspace packing (total 75,505,664 B ~ 72 MiB)
    char* ws = (char*)d_ws;
    float*    val  = (float*)(ws + 0);           // 16,777,216 B
    float*    qk   = (float*)(ws + 16777216);    // 33,554,432 B
    float*    wt   = (float*)(ws + 50331648);    //  5,242,880 B
    unsigned* cnt  = (unsigned*)(ws + 55574528); //      8,192 B
    unsigned* idx  = (unsigned*)(ws + 55582720); //  3,145,728 B
    float*    ao   = (float*)(ws + 58728448);    // 16,777,216 B -> end 75,505,664

    hipLaunchKernelGGL(k_transpose_wqk, dim3((KKTOT * OCH) / 256), dim3(256), 0, stream, w_qk, wt);
    hipLaunchKernelGGL(k_mask_csr, dim3(S_LEN), dim3(256), 0, stream, mask, cnt, idx);
    hipLaunchKernelGGL(k_value, dim3((BATCH * S_LEN) / 16, 4), dim3(256), 0, stream, x, w_v, b_v, val);
    hipLaunchKernelGGL(k_qkconv, dim3((BATCH * S_LEN) / 32, 8), dim3(256), 0, stream, x, wt, b_qk, qk);
    hipLaunchKernelGGL(k_attn, dim3(BATCH * NH * S_LEN), dim3(256), 0, stream, qk, val, cnt, idx, ao);
    hipLaunchKernelGGL(k_proj, dim3((BATCH * S_LEN) / 16), dim3(256), 0, stream, ao, w_proj, b_proj, out);
}

// Round 16
// 670.750 us; speedup vs baseline: 1.0553x; 1.0021x over previous
//
#include <hip/hip_runtime.h>
#include <hip/hip_bf16.h>

#define S_LEN 2048
#define BATCH 2
#define DIM 128
#define NH 8
#define HD 1024
#define QL 5
#define KKTOT 640   // DIM*QL
#define OCH 2048
#define MAXNNZ 384

// ---------------- transpose w_qk (O,I,T) -> (I*T, O) for coalesced GEMM reads
__global__ void k_transpose_wqk(const float* __restrict__ w, float* __restrict__ wt) {
    int i = blockIdx.x * 256 + threadIdx.x;   // i = kk*2048 + o
    if (i >= KKTOT * OCH) return;
    int kk = i >> 11;
    int o  = i & 2047;
    wt[i] = w[o * KKTOT + kk];
}

// ---------------- compact mask rows to CSR (deterministic ballot compaction)
__global__ void k_mask_csr(const float* __restrict__ mask, unsigned* __restrict__ cnt,
                           unsigned* __restrict__ idx) {
    __shared__ unsigned s_base;
    __shared__ unsigned s_wcnt[4];
    int r = blockIdx.x;
    int tid = threadIdx.x;
    int lane = tid & 63;
    int w = tid >> 6;
    if (tid == 0) s_base = 0;
    __syncthreads();
    for (int c0 = 0; c0 < S_LEN; c0 += 256) {
        int c = c0 + tid;
        bool act = mask[(size_t)r * S_LEN + c] > 0.5f;
        unsigned long long bal = __ballot(act);
        if (lane == 0) s_wcnt[w] = (unsigned)__popcll(bal);
        __syncthreads();
        unsigned off = s_base;
        for (int i = 0; i < w; i++) off += s_wcnt[i];
        off += (unsigned)__popcll(bal & ((1ull << lane) - 1ull));
        if (act && off < MAXNNZ) idx[r * MAXNNZ + off] = (unsigned)c;
        __syncthreads();
        if (tid == 0) s_base += s_wcnt[0] + s_wcnt[1] + s_wcnt[2] + s_wcnt[3];
        __syncthreads();
    }
    if (tid == 0) cnt[r] = (s_base < MAXNNZ) ? s_base : MAXNNZ;
}

// ---------------- value = x @ w_v + b_v   (B*S,128)x(128,1024)
// grid (BATCH*S/16, 4), block 256
__global__ void k_value(const float* __restrict__ x, const float* __restrict__ wv,
                        const float* __restrict__ bv, float* __restrict__ val) {
    __shared__ float xs[16][128];
    int bs0 = blockIdx.x * 16;
    int c = blockIdx.y * 256 + threadIdx.x;
    for (int t = threadIdx.x; t < 16 * 128; t += 256)
        xs[t >> 7][t & 127] = x[(size_t)(bs0 + (t >> 7)) * DIM + (t & 127)];
    __syncthreads();
    float acc[16];
#pragma unroll
    for (int r = 0; r < 16; r++) acc[r] = 0.f;
    for (int k = 0; k < 128; k += 4) {
        float w0 = wv[(k + 0) * HD + c];
        float w1 = wv[(k + 1) * HD + c];
        float w2 = wv[(k + 2) * HD + c];
        float w3 = wv[(k + 3) * HD + c];
#pragma unroll
        for (int r = 0; r < 16; r++) {
            float4 xv = *reinterpret_cast<const float4*>(&xs[r][k]);
            acc[r] += xv.x * w0 + xv.y * w1 + xv.z * w2 + xv.w * w3;
        }
    }
    float b = bv[c];
#pragma unroll
    for (int r = 0; r < 16; r++)
        val[(size_t)(bs0 + r) * HD + c] = acc[r] + b;
}

// ---------------- qk = causal_conv(x, w_qk) + b_qk  as GEMM with K=640
// grid (BATCH*S/32, 8), block 256
__global__ void k_qkconv(const float* __restrict__ x, const float* __restrict__ wt,
                         const float* __restrict__ bqk, float* __restrict__ qk) {
    __shared__ float xs[36][128];
    int bs0 = blockIdx.x * 32;
    int b = bs0 >> 11;
    int s0 = bs0 & 2047;
    int o = blockIdx.y * 256 + threadIdx.x;
    for (int t = threadIdx.x; t < 36 * 128; t += 256) {
        int rr = t >> 7, i = t & 127;
        int s = s0 - 4 + rr;
        float v = 0.f;
        if (s >= 0) v = x[((size_t)b * S_LEN + s) * DIM + i];
        xs[rr][i] = v;
    }
    __syncthreads();
    float acc[32];
    float bias = bqk[o];
#pragma unroll
    for (int r = 0; r < 32; r++) acc[r] = bias;
    for (int i = 0; i < 128; i += 2) {
        float2 xr[36];
#pragma unroll
        for (int rr = 0; rr < 36; rr++)
            xr[rr] = *reinterpret_cast<const float2*>(&xs[rr][i]);
#pragma unroll
        for (int t = 0; t < QL; t++) {
            float wA = wt[((i + 0) * QL + t) * OCH + o];
            float wB = wt[((i + 1) * QL + t) * OCH + o];
#pragma unroll
            for (int r = 0; r < 32; r++)
                acc[r] += xr[r + t].x * wA + xr[r + t].y * wB;
        }
    }
    for (int r = 0; r < 32; r++)
        qk[((size_t)bs0 + r) * OCH + o] = acc[r];
}

// ---------------- sparse attention + entmax15
// XCD-aware bid swizzle: XCD x owns original bids [x*4096,(x+1)*4096) = 2 (b,h)
// pairs -> per-XCD K/V working set ~4MB fits private L2 (was: full 64MB thrash).
__global__ void __launch_bounds__(256) k_attn(const float* __restrict__ qk,
                                              const float* __restrict__ val,
                                              const unsigned* __restrict__ cnt,
                                              const unsigned* __restrict__ idxbuf,
                                              float* __restrict__ attout) {
    __shared__ float qs[128];
    __shared__ float ssc[MAXNNZ];
    __shared__ unsigned sidx[MAXNNZ];
    __shared__ float4 pv4[8][32];
    __shared__ float red4[4];
    __shared__ float s_mx;
    int l = blockIdx.x;
    int bid = (l & 7) * 4096 + (l >> 3);   // XCD swizzle (32768 = 8 * 4096, bijective)
    int r = bid & (S_LEN - 1);
    int h = (bid >> 11) & (NH - 1);
    int b = bid >> 14;
    int tid = threadIdx.x;
    int lane = tid & 63;
    int wave = tid >> 6;
    int n = (int)cnt[r];
    const float scale = 0.08838834764831843f;  // 1/sqrt(128)

    if (tid < 128) qs[tid] = qk[((size_t)(b * S_LEN + r)) * OCH + h * 128 + tid];
    for (int j = tid; j < n; j += 256) sidx[j] = idxbuf[r * MAXNNZ + j];
    __syncthreads();

    // ---- phase 1: scores, 2 columns per 4-lane group iteration (MLP)
    {
        int grp = tid >> 2;          // 0..63
        int ll  = tid & 3;           // lane within group
        const float* kbase = qk + (size_t)b * S_LEN * OCH + HD + h * 128;
        for (int j0 = grp; j0 < n; j0 += 128) {
            int j1 = j0 + 64;
            bool has1 = j1 < n;
            const float* kp0 = kbase + ((size_t)sidx[j0]) * OCH;
            const float* kp1 = has1 ? kbase + ((size_t)sidx[j1]) * OCH : kp0;
            float p0 = 0.f, p1 = 0.f;
#pragma unroll
            for (int i = 0; i < 8; i++) {
                int m = (i * 4 + ll) << 2;                 // float offset
                float4 qv = *reinterpret_cast<const float4*>(&qs[m]);
                float4 k0 = *reinterpret_cast<const float4*>(kp0 + m);
                float4 k1 = *reinterpret_cast<const float4*>(kp1 + m);
                p0 += qv.x * k0.x + qv.y * k0.y + qv.z * k0.z + qv.w * k0.w;
                p1 += qv.x * k1.x + qv.y * k1.y + qv.z * k1.z + qv.w * k1.w;
            }
            p0 += __shfl_xor(p0, 1, 64);
            p0 += __shfl_xor(p0, 2, 64);
            p1 += __shfl_xor(p1, 1, 64);
            p1 += __shfl_xor(p1, 2, 64);
            if (ll == 0) {
                ssc[j0] = p0 * scale;
                if (has1) ssc[j1] = p1 * scale;
            }
        }
    }
    __syncthreads();

    // ---- phase 2a: block-wide max
    {
        float lmx = -3.0e38f;
        for (int j = tid; j < n; j += 256) lmx = fmaxf(lmx, ssc[j]);
#pragma unroll
        for (int off = 32; off >= 1; off >>= 1) lmx = fmaxf(lmx, __shfl_xor(lmx, off, 64));
        if (lane == 0) red4[wave] = lmx;
    }
    __syncthreads();
    if (tid == 0) s_mx = fmaxf(fmaxf(red4[0], red4[1]), fmaxf(red4[2], red4[3]));
    __syncthreads();
    float mx = s_mx;

    // ---- phase 2b: bisection on wave 0 (tree-summed, 26 iters)
    if (wave == 0) {
        float xl[6];
#pragma unroll
        for (int l2 = 0; l2 < 6; l2++) {
            int j = lane + 64 * l2;
            xl[l2] = (j < n) ? (ssc[j] - mx) * 0.5f : -1.0e30f;
        }
        float lo = -1.f, hi = 0.f;
        for (int it = 0; it < 26; it++) {
            float mid = 0.5f * (lo + hi);
            float d0 = fmaxf(xl[0] - mid, 0.f), d1 = fmaxf(xl[1] - mid, 0.f);
            float d2 = fmaxf(xl[2] - mid, 0.f), d3 = fmaxf(xl[3] - mid, 0.f);
            float d4 = fmaxf(xl[4] - mid, 0.f), d5 = fmaxf(xl[5] - mid, 0.f);
            float f = ((d0 * d0 + d1 * d1) + (d2 * d2 + d3 * d3)) + (d4 * d4 + d5 * d5);
#pragma unroll
            for (int off = 32; off >= 1; off >>= 1) f += __shfl_xor(f, off, 64);
            if (f > 1.f) lo = mid; else hi = mid;
        }
        float tau = 0.5f * (lo + hi);
#pragma unroll
        for (int l2 = 0; l2 < 6; l2++) {
            int j = lane + 64 * l2;
            if (j < n) {
                float d = fmaxf(xl[l2] - tau, 0.f);
                ssc[j] = d * d;
            }
        }
    }
    __syncthreads();

    // ---- phase 3: PV, 2 slots per iteration, dual accumulators (MLP)
    {
        int slot = tid >> 5;         // 0..7
        int dg   = tid & 31;         // float4 dim group 0..31
        const float4* vbase = reinterpret_cast<const float4*>(
                                  val + (size_t)b * S_LEN * HD + h * 128) + dg;
        float4 accA = {0.f, 0.f, 0.f, 0.f};
        float4 accB = {0.f, 0.f, 0.f, 0.f};
        int j = slot;
        for (; j + 8 < n; j += 16) {
            float wA = ssc[j];
            float wB = ssc[j + 8];
            float4 vA = vbase[(size_t)sidx[j] << 8];
            float4 vB = vbase[(size_t)sidx[j + 8] << 8];
            accA.x += wA * vA.x; accA.y += wA * vA.y; accA.z += wA * vA.z; accA.w += wA * vA.w;
            accB.x += wB * vB.x; accB.y += wB * vB.y; accB.z += wB * vB.z; accB.w += wB * vB.w;
        }
        if (j < n) {
            float wA = ssc[j];
            float4 vA = vbase[(size_t)sidx[j] << 8];
            accA.x += wA * vA.x; accA.y += wA * vA.y; accA.z += wA * vA.z; accA.w += wA * vA.w;
        }
        accA.x += accB.x; accA.y += accB.y; accA.z += accB.z; accA.w += accB.w;
        pv4[slot][dg] = accA;
    }
    __syncthreads();
    if (tid < 128) {
        int d4 = tid >> 2, comp = tid & 3;
        float a = 0.f;
#pragma unroll
        for (int s = 0; s < 8; s++) a += reinterpret_cast<const float*>(&pv4[s][d4])[comp];
        attout[((size_t)(b * S_LEN + r)) * HD + h * 128 + tid] = a;
    }
}

// ---------------- out = attout @ w_proj + b_proj, store FLOAT32
// grid BATCH*S/16, block 256 (2-way split-K x 128 cols)
__global__ void k_proj(const float* __restrict__ ao, const float* __restrict__ wp,
                       const float* __restrict__ bp, float* __restrict__ out) {
    __shared__ float xs[2][16][128];
    int bs0 = blockIdx.x * 16;
    int tid = threadIdx.x;
    int dout = tid & 127;
    int kh = tid >> 7;
    float acc[16];
#pragma unroll
    for (int r = 0; r < 16; r++) acc[r] = 0.f;
    for (int cc = 0; cc < 4; cc++) {
        int kb = (kh + 2 * cc) * 128;
        __syncthreads();
        for (int t = dout; t < 16 * 128; t += 128)
            xs[kh][t >> 7][t & 127] = ao[(size_t)(bs0 + (t >> 7)) * HD + kb + (t & 127)];
        __syncthreads();
        for (int k = 0; k < 128; k += 4) {
            float w0 = wp[(kb + k + 0) * DIM + dout];
            float w1 = wp[(kb + k + 1) * DIM + dout];
            float w2 = wp[(kb + k + 2) * DIM + dout];
            float w3 = wp[(kb + k + 3) * DIM + dout];
#pragma unroll
            for (int r = 0; r < 16; r++) {
                float4 xv = *reinterpret_cast<const float4*>(&xs[kh][r][k]);
                acc[r] += xv.x * w0 + xv.y * w1 + xv.z * w2 + xv.w * w3;
            }
        }
    }
    __syncthreads();
#pragma unroll
    for (int r = 0; r < 16; r++) xs[kh][r][dout] = acc[r];
    __syncthreads();
    if (kh == 0) {
        float bb = bp[dout];
        for (int r = 0; r < 16; r++)
            out[(size_t)(bs0 + r) * DIM + dout] = xs[0][r][dout] + xs[1][r][dout] + bb;
    }
}

extern "C" void kernel_launch(void* const* d_in, const int* in_sizes, int n_in,
                              void* d_out, int out_size, void* d_ws, size_t ws_size,
                              hipStream_t stream) {
    const float* x      = (const float*)d_in[0];
    const float* mask   = (const float*)d_in[1];
    const float* w_qk   = (const float*)d_in[2];
    const float* b_qk   = (const float*)d_in[3];
    const float* w_v    = (const float*)d_in[4];
    const float* b_v    = (const float*)d_in[5];
    const float* w_proj = (const float*)d_in[6];
    const float* b_proj = (const float*)d_in[7];
    float* out = (float*)d_out;     // reference output dtype is FLOAT32

    // tight workspace packing (total 75,505,664 B ~ 72 MiB)
    char* ws = (char*)d_ws;
    float*    val  = (float*)(ws + 0);           // 16,777,216 B
    float*    qk   = (float*)(ws + 16777216);    // 33,554,432 B
    float*    wt   = (float*)(ws + 50331648);    //  5,242,880 B
    unsigned* cnt  = (unsigned*)(ws + 55574528); //      8,192 B
    unsigned* idx  = (unsigned*)(ws + 55582720); //  3,145,728 B
    float*    ao   = (float*)(ws + 58728448);    // 16,777,216 B -> end 75,505,664

    hipLaunchKernelGGL(k_transpose_wqk, dim3((KKTOT * OCH) / 256), dim3(256), 0, stream, w_qk, wt);
    hipLaunchKernelGGL(k_mask_csr, dim3(S_LEN), dim3(256), 0, stream, mask, cnt, idx);
    hipLaunchKernelGGL(k_value, dim3((BATCH * S_LEN) / 16, 4), dim3(256), 0, stream, x, w_v, b_v, val);
    hipLaunchKernelGGL(k_qkconv, dim3((BATCH * S_LEN) / 32, 8), dim3(256), 0, stream, x, wt, b_qk, qk);
    hipLaunchKernelGGL(k_attn, dim3(BATCH * NH * S_LEN), dim3(256), 0, stream, qk, val, cnt, idx, ao);
    hipLaunchKernelGGL(k_proj, dim3((BATCH * S_LEN) / 16), dim3(256), 0, stream, ao, w_proj, b_proj, out);
}

// Round 17
// 656.558 us; speedup vs baseline: 1.0781x; 1.0216x over previous
//
#include <hip/hip_runtime.h>
#include <hip/hip_bf16.h>

#define S_LEN 2048
#define BATCH 2
#define DIM 128
#define NH 8
#define HD 1024
#define QL 5
#define KKTOT 640   // DIM*QL
#define OCH 2048
#define MAXNNZ 384

// ---------------- transpose w_qk (O,I,T) -> (I*T, O) for coalesced GEMM reads
__global__ void k_transpose_wqk(const float* __restrict__ w, float* __restrict__ wt) {
    int i = blockIdx.x * 256 + threadIdx.x;   // i = kk*2048 + o
    if (i >= KKTOT * OCH) return;
    int kk = i >> 11;
    int o  = i & 2047;
    wt[i] = w[o * KKTOT + kk];
}

// ---------------- compact mask rows to CSR (deterministic ballot compaction)
__global__ void k_mask_csr(const float* __restrict__ mask, unsigned* __restrict__ cnt,
                           unsigned* __restrict__ idx) {
    __shared__ unsigned s_base;
    __shared__ unsigned s_wcnt[4];
    int r = blockIdx.x;
    int tid = threadIdx.x;
    int lane = tid & 63;
    int w = tid >> 6;
    if (tid == 0) s_base = 0;
    __syncthreads();
    for (int c0 = 0; c0 < S_LEN; c0 += 256) {
        int c = c0 + tid;
        bool act = mask[(size_t)r * S_LEN + c] > 0.5f;
        unsigned long long bal = __ballot(act);
        if (lane == 0) s_wcnt[w] = (unsigned)__popcll(bal);
        __syncthreads();
        unsigned off = s_base;
        for (int i = 0; i < w; i++) off += s_wcnt[i];
        off += (unsigned)__popcll(bal & ((1ull << lane) - 1ull));
        if (act && off < MAXNNZ) idx[r * MAXNNZ + off] = (unsigned)c;
        __syncthreads();
        if (tid == 0) s_base += s_wcnt[0] + s_wcnt[1] + s_wcnt[2] + s_wcnt[3];
        __syncthreads();
    }
    if (tid == 0) cnt[r] = (s_base < MAXNNZ) ? s_base : MAXNNZ;
}

// ---------------- value = x @ w_v + b_v   (B*S,128)x(128,1024)
// grid (BATCH*S/16, 4), block 256
__global__ void k_value(const float* __restrict__ x, const float* __restrict__ wv,
                        const float* __restrict__ bv, float* __restrict__ val) {
    __shared__ float xs[16][128];
    int bs0 = blockIdx.x * 16;
    int c = blockIdx.y * 256 + threadIdx.x;
    for (int t = threadIdx.x; t < 16 * 128; t += 256)
        xs[t >> 7][t & 127] = x[(size_t)(bs0 + (t >> 7)) * DIM + (t & 127)];
    __syncthreads();
    float acc[16];
#pragma unroll
    for (int r = 0; r < 16; r++) acc[r] = 0.f;
    for (int k = 0; k < 128; k += 4) {
        float w0 = wv[(k + 0) * HD + c];
        float w1 = wv[(k + 1) * HD + c];
        float w2 = wv[(k + 2) * HD + c];
        float w3 = wv[(k + 3) * HD + c];
#pragma unroll
        for (int r = 0; r < 16; r++) {
            float4 xv = *reinterpret_cast<const float4*>(&xs[r][k]);
            acc[r] += xv.x * w0 + xv.y * w1 + xv.z * w2 + xv.w * w3;
        }
    }
    float b = bv[c];
#pragma unroll
    for (int r = 0; r < 16; r++)
        val[(size_t)(bs0 + r) * HD + c] = acc[r] + b;
}

// ---------------- qk = causal_conv(x, w_qk) + b_qk  as GEMM with K=640
// grid (BATCH*S/32, 8), block 256
__global__ void k_qkconv(const float* __restrict__ x, const float* __restrict__ wt,
                         const float* __restrict__ bqk, float* __restrict__ qk) {
    __shared__ float xs[36][128];
    int bs0 = blockIdx.x * 32;
    int b = bs0 >> 11;
    int s0 = bs0 & 2047;
    int o = blockIdx.y * 256 + threadIdx.x;
    for (int t = threadIdx.x; t < 36 * 128; t += 256) {
        int rr = t >> 7, i = t & 127;
        int s = s0 - 4 + rr;
        float v = 0.f;
        if (s >= 0) v = x[((size_t)b * S_LEN + s) * DIM + i];
        xs[rr][i] = v;
    }
    __syncthreads();
    float acc[32];
    float bias = bqk[o];
#pragma unroll
    for (int r = 0; r < 32; r++) acc[r] = bias;
    for (int i = 0; i < 128; i += 2) {
        float2 xr[36];
#pragma unroll
        for (int rr = 0; rr < 36; rr++)
            xr[rr] = *reinterpret_cast<const float2*>(&xs[rr][i]);
#pragma unroll
        for (int t = 0; t < QL; t++) {
            float wA = wt[((i + 0) * QL + t) * OCH + o];
            float wB = wt[((i + 1) * QL + t) * OCH + o];
#pragma unroll
            for (int r = 0; r < 32; r++)
                acc[r] += xr[r + t].x * wA + xr[r + t].y * wB;
        }
    }
    for (int r = 0; r < 32; r++)
        qk[((size_t)bs0 + r) * OCH + o] = acc[r];
}

// ---------------- sparse attention + entmax15
// Phase 1: q hoisted to 8 float4 REGISTERS per lane (kills ~170 DS instr/wave,
// the co-dominant resource). Single-column loop to stay <= 64 VGPR.
__global__ void __launch_bounds__(256) k_attn(const float* __restrict__ qk,
                                              const float* __restrict__ val,
                                              const unsigned* __restrict__ cnt,
                                              const unsigned* __restrict__ idxbuf,
                                              float* __restrict__ attout) {
    __shared__ float qs[128];
    __shared__ float ssc[MAXNNZ];
    __shared__ unsigned sidx[MAXNNZ];
    __shared__ float4 pv4[8][32];
    __shared__ float red4[4];
    __shared__ float s_mx;
    int l = blockIdx.x;
    int bid = (l & 7) * 4096 + (l >> 3);   // XCD swizzle (32768 = 8 * 4096, bijective)
    int r = bid & (S_LEN - 1);
    int h = (bid >> 11) & (NH - 1);
    int b = bid >> 14;
    int tid = threadIdx.x;
    int lane = tid & 63;
    int wave = tid >> 6;
    int n = (int)cnt[r];
    const float scale = 0.08838834764831843f;  // 1/sqrt(128)

    if (tid < 128) qs[tid] = qk[((size_t)(b * S_LEN + r)) * OCH + h * 128 + tid];
    for (int j = tid; j < n; j += 256) sidx[j] = idxbuf[r * MAXNNZ + j];
    __syncthreads();

    // ---- phase 1: scores; q slice in registers, one column per 4-lane group
    {
        int grp = tid >> 2;          // 0..63
        int ll  = tid & 3;           // lane within group
        float4 qreg[8];
#pragma unroll
        for (int i = 0; i < 8; i++)
            qreg[i] = *reinterpret_cast<const float4*>(&qs[(i * 4 + ll) << 2]);
        const float* kbase = qk + (size_t)b * S_LEN * OCH + HD + h * 128;
        for (int j = grp; j < n; j += 64) {
            const float* kp = kbase + ((size_t)sidx[j]) * OCH;
            float p = 0.f;
#pragma unroll
            for (int i = 0; i < 8; i++) {
                float4 kv = *reinterpret_cast<const float4*>(kp + ((i * 4 + ll) << 2));
                p += qreg[i].x * kv.x + qreg[i].y * kv.y + qreg[i].z * kv.z + qreg[i].w * kv.w;
            }
            p += __shfl_xor(p, 1, 64);
            p += __shfl_xor(p, 2, 64);
            if (ll == 0) ssc[j] = p * scale;
        }
    }
    __syncthreads();

    // ---- phase 2a: block-wide max
    {
        float lmx = -3.0e38f;
        for (int j = tid; j < n; j += 256) lmx = fmaxf(lmx, ssc[j]);
#pragma unroll
        for (int off = 32; off >= 1; off >>= 1) lmx = fmaxf(lmx, __shfl_xor(lmx, off, 64));
        if (lane == 0) red4[wave] = lmx;
    }
    __syncthreads();
    if (tid == 0) s_mx = fmaxf(fmaxf(red4[0], red4[1]), fmaxf(red4[2], red4[3]));
    __syncthreads();
    float mx = s_mx;

    // ---- phase 2b: bisection on wave 0 (tree-summed, 26 iters)
    if (wave == 0) {
        float xl[6];
#pragma unroll
        for (int l2 = 0; l2 < 6; l2++) {
            int j = lane + 64 * l2;
            xl[l2] = (j < n) ? (ssc[j] - mx) * 0.5f : -1.0e30f;
        }
        float lo = -1.f, hi = 0.f;
        for (int it = 0; it < 26; it++) {
            float mid = 0.5f * (lo + hi);
            float d0 = fmaxf(xl[0] - mid, 0.f), d1 = fmaxf(xl[1] - mid, 0.f);
            float d2 = fmaxf(xl[2] - mid, 0.f), d3 = fmaxf(xl[3] - mid, 0.f);
            float d4 = fmaxf(xl[4] - mid, 0.f), d5 = fmaxf(xl[5] - mid, 0.f);
            float f = ((d0 * d0 + d1 * d1) + (d2 * d2 + d3 * d3)) + (d4 * d4 + d5 * d5);
#pragma unroll
            for (int off = 32; off >= 1; off >>= 1) f += __shfl_xor(f, off, 64);
            if (f > 1.f) lo = mid; else hi = mid;
        }
        float tau = 0.5f * (lo + hi);
#pragma unroll
        for (int l2 = 0; l2 < 6; l2++) {
            int j = lane + 64 * l2;
            if (j < n) {
                float d = fmaxf(xl[l2] - tau, 0.f);
                ssc[j] = d * d;
            }
        }
    }
    __syncthreads();

    // ---- phase 3: PV, 2 slots per iteration, dual accumulators
    {
        int slot = tid >> 5;         // 0..7
        int dg   = tid & 31;         // float4 dim group 0..31
        const float4* vbase = reinterpret_cast<const float4*>(
                                  val + (size_t)b * S_LEN * HD + h * 128) + dg;
        float4 accA = {0.f, 0.f, 0.f, 0.f};
        float4 accB = {0.f, 0.f, 0.f, 0.f};
        int j = slot;
        for (; j + 8 < n; j += 16) {
            float wA = ssc[j];
            float wB = ssc[j + 8];
            float4 vA = vbase[(size_t)sidx[j] << 8];
            float4 vB = vbase[(size_t)sidx[j + 8] << 8];
            accA.x += wA * vA.x; accA.y += wA * vA.y; accA.z += wA * vA.z; accA.w += wA * vA.w;
            accB.x += wB * vB.x; accB.y += wB * vB.y; accB.z += wB * vB.z; accB.w += wB * vB.w;
        }
        if (j < n) {
            float wA = ssc[j];
            float4 vA = vbase[(size_t)sidx[j] << 8];
            accA.x += wA * vA.x; accA.y += wA * vA.y; accA.z += wA * vA.z; accA.w += wA * vA.w;
        }
        accA.x += accB.x; accA.y += accB.y; accA.z += accB.z; accA.w += accB.w;
        pv4[slot][dg] = accA;
    }
    __syncthreads();
    if (tid < 128) {
        int d4 = tid >> 2, comp = tid & 3;
        float a = 0.f;
#pragma unroll
        for (int s = 0; s < 8; s++) a += reinterpret_cast<const float*>(&pv4[s][d4])[comp];
        attout[((size_t)(b * S_LEN + r)) * HD + h * 128 + tid] = a;
    }
}

// ---------------- out = attout @ w_proj + b_proj, store FLOAT32
// grid BATCH*S/16, block 256 (2-way split-K x 128 cols)
__global__ void k_proj(const float* __restrict__ ao, const float* __restrict__ wp,
                       const float* __restrict__ bp, float* __restrict__ out) {
    __shared__ float xs[2][16][128];
    int bs0 = blockIdx.x * 16;
    int tid = threadIdx.x;
    int dout = tid & 127;
    int kh = tid >> 7;
    float acc[16];
#pragma unroll
    for (int r = 0; r < 16; r++) acc[r] = 0.f;
    for (int cc = 0; cc < 4; cc++) {
        int kb = (kh + 2 * cc) * 128;
        __syncthreads();
        for (int t = dout; t < 16 * 128; t += 128)
            xs[kh][t >> 7][t & 127] = ao[(size_t)(bs0 + (t >> 7)) * HD + kb + (t & 127)];
        __syncthreads();
        for (int k = 0; k < 128; k += 4) {
            float w0 = wp[(kb + k + 0) * DIM + dout];
            float w1 = wp[(kb + k + 1) * DIM + dout];
            float w2 = wp[(kb + k + 2) * DIM + dout];
            float w3 = wp[(kb + k + 3) * DIM + dout];
#pragma unroll
            for (int r = 0; r < 16; r++) {
                float4 xv = *reinterpret_cast<const float4*>(&xs[kh][r][k]);
                acc[r] += xv.x * w0 + xv.y * w1 + xv.z * w2 + xv.w * w3;
            }
        }
    }
    __syncthreads();
#pragma unroll
    for (int r = 0; r < 16; r++) xs[kh][r][dout] = acc[r];
    __syncthreads();
    if (kh == 0) {
        float bb = bp[dout];
        for (int r = 0; r < 16; r++)
            out[(size_t)(bs0 + r) * DIM + dout] = xs[0][r][dout] + xs[1][r][dout] + bb;
    }
}

extern "C" void kernel_launch(void* const* d_in, const int* in_sizes, int n_in,
                              void* d_out, int out_size, void* d_ws, size_t ws_size,
                              hipStream_t stream) {
    const float* x      = (const float*)d_in[0];
    const float* mask   = (const float*)d_in[1];
    const float* w_qk   = (const float*)d_in[2];
    const float* b_qk   = (const float*)d_in[3];
    const float* w_v    = (const float*)d_in[4];
    const float* b_v    = (const float*)d_in[5];
    const float* w_proj = (const float*)d_in[6];
    const float* b_proj = (const float*)d_in[7];
    float* out = (float*)d_out;     // reference output dtype is FLOAT32

    // tight workspace packing (total 75,505,664 B ~ 72 MiB)
    char* ws = (char*)d_ws;
    float*    val  = (float*)(ws + 0);           // 16,777,216 B
    float*    qk   = (float*)(ws + 16777216);    // 33,554,432 B
    float*    wt   = (float*)(ws + 50331648);    //  5,242,880 B
    unsigned* cnt  = (unsigned*)(ws + 55574528); //      8,192 B
    unsigned* idx  = (unsigned*)(ws + 55582720); //  3,145,728 B
    float*    ao   = (float*)(ws + 58728448);    // 16,777,216 B -> end 75,505,664

    hipLaunchKernelGGL(k_transpose_wqk, dim3((KKTOT * OCH) / 256), dim3(256), 0, stream, w_qk, wt);
    hipLaunchKernelGGL(k_mask_csr, dim3(S_LEN), dim3(256), 0, stream, mask, cnt, idx);
    hipLaunchKernelGGL(k_value, dim3((BATCH * S_LEN) / 16, 4), dim3(256), 0, stream, x, w_v, b_v, val);
    hipLaunchKernelGGL(k_qkconv, dim3((BATCH * S_LEN) / 32, 8), dim3(256), 0, stream, x, wt, b_qk, qk);
    hipLaunchKernelGGL(k_attn, dim3(BATCH * NH * S_LEN), dim3(256), 0, stream, qk, val, cnt, idx, ao);
    hipLaunchKernelGGL(k_proj, dim3((BATCH * S_LEN) / 16), dim3(256), 0, stream, ao, w_proj, b_proj, out);
}

// Round 18
// 551.774 us; speedup vs baseline: 1.2829x; 1.1899x over previous
//
#include <hip/hip_runtime.h>
#include <hip/hip_bf16.h>
#include <hip/hip_fp16.h>

#define S_LEN 2048
#define BATCH 2
#define DIM 128
#define NH 8
#define HD 1024
#define QL 5
#define KKTOT 640   // DIM*QL
#define OCH 2048
#define MAXNNZ 384

typedef _Float16 hv2 __attribute__((ext_vector_type(2)));

#if defined(__has_builtin)
#  if __has_builtin(__builtin_amdgcn_fdot2)
#    define USE_FDOT2 1
#  endif
#endif
#ifndef USE_FDOT2
#  define USE_FDOT2 0
#endif

// ---------------- transpose w_qk (O,I,T) -> (I*T, O) for coalesced GEMM reads
__global__ void k_transpose_wqk(const float* __restrict__ w, float* __restrict__ wt) {
    int i = blockIdx.x * 256 + threadIdx.x;   // i = kk*2048 + o
    if (i >= KKTOT * OCH) return;
    int kk = i >> 11;
    int o  = i & 2047;
    wt[i] = w[o * KKTOT + kk];
}

// ---------------- compact mask rows to CSR (deterministic ballot compaction)
__global__ void k_mask_csr(const float* __restrict__ mask, unsigned* __restrict__ cnt,
                           unsigned* __restrict__ idx) {
    __shared__ unsigned s_base;
    __shared__ unsigned s_wcnt[4];
    int r = blockIdx.x;
    int tid = threadIdx.x;
    int lane = tid & 63;
    int w = tid >> 6;
    if (tid == 0) s_base = 0;
    __syncthreads();
    for (int c0 = 0; c0 < S_LEN; c0 += 256) {
        int c = c0 + tid;
        bool act = mask[(size_t)r * S_LEN + c] > 0.5f;
        unsigned long long bal = __ballot(act);
        if (lane == 0) s_wcnt[w] = (unsigned)__popcll(bal);
        __syncthreads();
        unsigned off = s_base;
        for (int i = 0; i < w; i++) off += s_wcnt[i];
        off += (unsigned)__popcll(bal & ((1ull << lane) - 1ull));
        if (act && off < MAXNNZ) idx[r * MAXNNZ + off] = (unsigned)c;
        __syncthreads();
        if (tid == 0) s_base += s_wcnt[0] + s_wcnt[1] + s_wcnt[2] + s_wcnt[3];
        __syncthreads();
    }
    if (tid == 0) cnt[r] = (s_base < MAXNNZ) ? s_base : MAXNNZ;
}

// ---------------- fp32 -> fp16 bulk convert (float4 -> 4 halves per thread)
__global__ void k_cvt(const float4* __restrict__ src, ushort4* __restrict__ dst, int n4) {
    int i = blockIdx.x * 256 + threadIdx.x;
    if (i >= n4) return;
    float4 v = src[i];
    ushort4 o;
    o.x = __half_as_ushort(__float2half(v.x));
    o.y = __half_as_ushort(__float2half(v.y));
    o.z = __half_as_ushort(__float2half(v.z));
    o.w = __half_as_ushort(__float2half(v.w));
    dst[i] = o;
}

// ---------------- value = x @ w_v + b_v   (B*S,128)x(128,1024)
// grid (BATCH*S/16, 4), block 256
__global__ void k_value(const float* __restrict__ x, const float* __restrict__ wv,
                        const float* __restrict__ bv, float* __restrict__ val) {
    __shared__ float xs[16][128];
    int bs0 = blockIdx.x * 16;
    int c = blockIdx.y * 256 + threadIdx.x;
    for (int t = threadIdx.x; t < 16 * 128; t += 256)
        xs[t >> 7][t & 127] = x[(size_t)(bs0 + (t >> 7)) * DIM + (t & 127)];
    __syncthreads();
    float acc[16];
#pragma unroll
    for (int r = 0; r < 16; r++) acc[r] = 0.f;
    for (int k = 0; k < 128; k += 4) {
        float w0 = wv[(k + 0) * HD + c];
        float w1 = wv[(k + 1) * HD + c];
        float w2 = wv[(k + 2) * HD + c];
        float w3 = wv[(k + 3) * HD + c];
#pragma unroll
        for (int r = 0; r < 16; r++) {
            float4 xv = *reinterpret_cast<const float4*>(&xs[r][k]);
            acc[r] += xv.x * w0 + xv.y * w1 + xv.z * w2 + xv.w * w3;
        }
    }
    float b = bv[c];
#pragma unroll
    for (int r = 0; r < 16; r++)
        val[(size_t)(bs0 + r) * HD + c] = acc[r] + b;
}

// ---------------- qk = causal_conv(x, w_qk) + b_qk  as GEMM with K=640
// grid (BATCH*S/32, 8), block 256
__global__ void k_qkconv(const float* __restrict__ x, const float* __restrict__ wt,
                         const float* __restrict__ bqk, float* __restrict__ qk) {
    __shared__ float xs[36][128];
    int bs0 = blockIdx.x * 32;
    int b = bs0 >> 11;
    int s0 = bs0 & 2047;
    int o = blockIdx.y * 256 + threadIdx.x;
    for (int t = threadIdx.x; t < 36 * 128; t += 256) {
        int rr = t >> 7, i = t & 127;
        int s = s0 - 4 + rr;
        float v = 0.f;
        if (s >= 0) v = x[((size_t)b * S_LEN + s) * DIM + i];
        xs[rr][i] = v;
    }
    __syncthreads();
    float acc[32];
    float bias = bqk[o];
#pragma unroll
    for (int r = 0; r < 32; r++) acc[r] = bias;
    for (int i = 0; i < 128; i += 2) {
        float2 xr[36];
#pragma unroll
        for (int rr = 0; rr < 36; rr++)
            xr[rr] = *reinterpret_cast<const float2*>(&xs[rr][i]);
#pragma unroll
        for (int t = 0; t < QL; t++) {
            float wA = wt[((i + 0) * QL + t) * OCH + o];
            float wB = wt[((i + 1) * QL + t) * OCH + o];
#pragma unroll
            for (int r = 0; r < 32; r++)
                acc[r] += xr[r + t].x * wA + xr[r + t].y * wB;
        }
    }
    for (int r = 0; r < 32; r++)
        qk[((size_t)bs0 + r) * OCH + o] = acc[r];
}

// ---------------- sparse attention + entmax15, fp16 K/V gathers
__global__ void __launch_bounds__(256) k_attn(const _Float16* __restrict__ qk16,
                                              const _Float16* __restrict__ val16,
                                              const unsigned* __restrict__ cnt,
                                              const unsigned* __restrict__ idxbuf,
                                              float* __restrict__ attout) {
    __shared__ float ssc[MAXNNZ];
    __shared__ unsigned sidx[MAXNNZ];
    __shared__ float pvs[16][128];
    __shared__ float red4[4];
    __shared__ float s_mx;
    int l = blockIdx.x;
    int bid = (l & 7) * 4096 + (l >> 3);   // XCD swizzle (32768 = 8 * 4096, bijective)
    int r = bid & (S_LEN - 1);
    int h = (bid >> 11) & (NH - 1);
    int b = bid >> 14;
    int tid = threadIdx.x;
    int lane = tid & 63;
    int wave = tid >> 6;
    int n = (int)cnt[r];
    const float scale = 0.08838834764831843f;  // 1/sqrt(128)

    for (int j = tid; j < n; j += 256) sidx[j] = idxbuf[r * MAXNNZ + j];
    __syncthreads();

    // ---- phase 1: scores; fp16 q in registers, fp16 K gathers, packed dot
    {
        int grp = tid >> 2;          // 0..63
        int ll  = tid & 3;           // lane within group
        const uint4* q16 = reinterpret_cast<const uint4*>(
                               qk16 + ((size_t)(b * S_LEN + r)) * OCH + h * 128);
        uint4 qreg[4];
#pragma unroll
        for (int i = 0; i < 4; i++) qreg[i] = q16[i * 4 + ll];
        const _Float16* kbase = qk16 + (size_t)b * S_LEN * OCH + HD + h * 128;
        for (int j = grp; j < n; j += 64) {
            const uint4* kp = reinterpret_cast<const uint4*>(kbase + (size_t)sidx[j] * OCH);
            float p = 0.f;
#pragma unroll
            for (int i = 0; i < 4; i++) {
                uint4 kv = kp[i * 4 + ll];
                const hv2* ka = reinterpret_cast<const hv2*>(&kv);
                const hv2* qa = reinterpret_cast<const hv2*>(&qreg[i]);
#if USE_FDOT2
                p = __builtin_amdgcn_fdot2(qa[0], ka[0], p, false);
                p = __builtin_amdgcn_fdot2(qa[1], ka[1], p, false);
                p = __builtin_amdgcn_fdot2(qa[2], ka[2], p, false);
                p = __builtin_amdgcn_fdot2(qa[3], ka[3], p, false);
#else
#pragma unroll
                for (int k2 = 0; k2 < 4; k2++) {
                    p += (float)qa[k2][0] * (float)ka[k2][0];
                    p += (float)qa[k2][1] * (float)ka[k2][1];
                }
#endif
            }
            p += __shfl_xor(p, 1, 64);
            p += __shfl_xor(p, 2, 64);
            if (ll == 0) ssc[j] = p * scale;
        }
    }
    __syncthreads();

    // ---- phase 2a: block-wide max
    {
        float lmx = -3.0e38f;
        for (int j = tid; j < n; j += 256) lmx = fmaxf(lmx, ssc[j]);
#pragma unroll
        for (int off = 32; off >= 1; off >>= 1) lmx = fmaxf(lmx, __shfl_xor(lmx, off, 64));
        if (lane == 0) red4[wave] = lmx;
    }
    __syncthreads();
    if (tid == 0) s_mx = fmaxf(fmaxf(red4[0], red4[1]), fmaxf(red4[2], red4[3]));
    __syncthreads();
    float mx = s_mx;

    // ---- phase 2b: bisection on wave 0 (tree-summed, 26 iters)
    if (wave == 0) {
        float xl[6];
#pragma unroll
        for (int l2 = 0; l2 < 6; l2++) {
            int j = lane + 64 * l2;
            xl[l2] = (j < n) ? (ssc[j] - mx) * 0.5f : -1.0e30f;
        }
        float lo = -1.f, hi = 0.f;
        for (int it = 0; it < 26; it++) {
            float mid = 0.5f * (lo + hi);
            float d0 = fmaxf(xl[0] - mid, 0.f), d1 = fmaxf(xl[1] - mid, 0.f);
            float d2 = fmaxf(xl[2] - mid, 0.f), d3 = fmaxf(xl[3] - mid, 0.f);
            float d4 = fmaxf(xl[4] - mid, 0.f), d5 = fmaxf(xl[5] - mid, 0.f);
            float f = ((d0 * d0 + d1 * d1) + (d2 * d2 + d3 * d3)) + (d4 * d4 + d5 * d5);
#pragma unroll
            for (int off = 32; off >= 1; off >>= 1) f += __shfl_xor(f, off, 64);
            if (f > 1.f) lo = mid; else hi = mid;
        }
        float tau = 0.5f * (lo + hi);
#pragma unroll
        for (int l2 = 0; l2 < 6; l2++) {
            int j = lane + 64 * l2;
            if (j < n) {
                float d = fmaxf(xl[l2] - tau, 0.f);
                ssc[j] = d * d;
            }
        }
    }
    __syncthreads();

    // ---- phase 3: PV, fp16 V — 16 column-slots x 16 dim-groups (8 dims each)
    {
        int slot = tid >> 4;         // 0..15
        int dg   = tid & 15;         // 0..15, dims dg*8..dg*8+7
        const uint4* vbase = reinterpret_cast<const uint4*>(
                                 val16 + (size_t)b * S_LEN * HD + h * 128) + dg;
        float acc[8];
#pragma unroll
        for (int k = 0; k < 8; k++) acc[k] = 0.f;
        for (int j = slot; j < n; j += 16) {
            float w = ssc[j];
            uint4 vv = vbase[(size_t)sidx[j] << 7];     // row stride 1024 halves = 128 uint4
            const __half2* va = reinterpret_cast<const __half2*>(&vv);
#pragma unroll
            for (int k = 0; k < 4; k++) {
                float2 f = __half22float2(va[k]);
                acc[2 * k]     += w * f.x;
                acc[2 * k + 1] += w * f.y;
            }
        }
#pragma unroll
        for (int k = 0; k < 8; k++) pvs[slot][dg * 8 + k] = acc[k];
    }
    __syncthreads();
    if (tid < 128) {
        float a = 0.f;
#pragma unroll
        for (int s = 0; s < 16; s++) a += pvs[s][tid];
        attout[((size_t)(b * S_LEN + r)) * HD + h * 128 + tid] = a;
    }
}

// ---------------- out = attout @ w_proj + b_proj, store FLOAT32
// grid BATCH*S/16, block 256 (2-way split-K x 128 cols)
__global__ void k_proj(const float* __restrict__ ao, const float* __restrict__ wp,
                       const float* __restrict__ bp, float* __restrict__ out) {
    __shared__ float xs[2][16][128];
    int bs0 = blockIdx.x * 16;
    int tid = threadIdx.x;
    int dout = tid & 127;
    int kh = tid >> 7;
    float acc[16];
#pragma unroll
    for (int r = 0; r < 16; r++) acc[r] = 0.f;
    for (int cc = 0; cc < 4; cc++) {
        int kb = (kh + 2 * cc) * 128;
        __syncthreads();
        for (int t = dout; t < 16 * 128; t += 128)
            xs[kh][t >> 7][t & 127] = ao[(size_t)(bs0 + (t >> 7)) * HD + kb + (t & 127)];
        __syncthreads();
        for (int k = 0; k < 128; k += 4) {
            float w0 = wp[(kb + k + 0) * DIM + dout];
            float w1 = wp[(kb + k + 1) * DIM + dout];
            float w2 = wp[(kb + k + 2) * DIM + dout];
            float w3 = wp[(kb + k + 3) * DIM + dout];
#pragma unroll
            for (int r = 0; r < 16; r++) {
                float4 xv = *reinterpret_cast<const float4*>(&xs[kh][r][k]);
                acc[r] += xv.x * w0 + xv.y * w1 + xv.z * w2 + xv.w * w3;
            }
        }
    }
    __syncthreads();
#pragma unroll
    for (int r = 0; r < 16; r++) xs[kh][r][dout] = acc[r];
    __syncthreads();
    if (kh == 0) {
        float bb = bp[dout];
        for (int r = 0; r < 16; r++)
            out[(size_t)(bs0 + r) * DIM + dout] = xs[0][r][dout] + xs[1][r][dout] + bb;
    }
}

extern "C" void kernel_launch(void* const* d_in, const int* in_sizes, int n_in,
                              void* d_out, int out_size, void* d_ws, size_t ws_size,
                              hipStream_t stream) {
    const float* x      = (const float*)d_in[0];
    const float* mask   = (const float*)d_in[1];
    const float* w_qk   = (const float*)d_in[2];
    const float* b_qk   = (const float*)d_in[3];
    const float* w_v    = (const float*)d_in[4];
    const float* b_v    = (const float*)d_in[5];
    const float* w_proj = (const float*)d_in[6];
    const float* b_proj = (const float*)d_in[7];
    float* out = (float*)d_out;     // reference output dtype is FLOAT32

    char* ws = (char*)d_ws;
    float*     val   = (float*)(ws + 0);            // 16,777,216 B
    float*     qk    = (float*)(ws + 16777216);     // 33,554,432 B
    float*     wt    = (float*)(ws + 50331648);     //  5,242,880 B
    unsigned*  cnt   = (unsigned*)(ws + 55574528);  //      8,192 B
    unsigned*  idx   = (unsigned*)(ws + 55582720);  //  3,145,728 B
    float*     ao    = (float*)(ws + 58728448);     // 16,777,216 B
    _Float16*  qk16  = (_Float16*)(ws + 75505664);  // 16,777,216 B
    _Float16*  val16 = (_Float16*)(ws + 92282880);  //  8,388,608 B -> end 100,671,488

    hipLaunchKernelGGL(k_transpose_wqk, dim3((KKTOT * OCH) / 256), dim3(256), 0, stream, w_qk, wt);
    hipLaunchKernelGGL(k_mask_csr, dim3(S_LEN), dim3(256), 0, stream, mask, cnt, idx);
    hipLaunchKernelGGL(k_value, dim3((BATCH * S_LEN) / 16, 4), dim3(256), 0, stream, x, w_v, b_v, val);
    hipLaunchKernelGGL(k_qkconv, dim3((BATCH * S_LEN) / 32, 8), dim3(256), 0, stream, x, wt, b_qk, qk);
    hipLaunchKernelGGL(k_cvt, dim3((BATCH * S_LEN * OCH / 4) / 256), dim3(256), 0, stream,
                       (const float4*)qk, (ushort4*)qk16, BATCH * S_LEN * OCH / 4);
    hipLaunchKernelGGL(k_cvt, dim3((BATCH * S_LEN * HD / 4) / 256), dim3(256), 0, stream,
                       (const float4*)val, (ushort4*)val16, BATCH * S_LEN * HD / 4);
    hipLaunchKernelGGL(k_attn, dim3(BATCH * NH * S_LEN), dim3(256), 0, stream, qk16, val16, cnt, idx, ao);
    hipLaunchKernelGGL(k_proj, dim3((BATCH * S_LEN) / 16), dim3(256), 0, stream, ao, w_proj, b_proj, out);
}

// Round 19
// 426.861 us; speedup vs baseline: 1.6583x; 1.2926x over previous
//
#include <hip/hip_runtime.h>
#include <hip/hip_bf16.h>
#include <hip/hip_fp16.h>

#define S_LEN 2048
#define BATCH 2
#define DIM 128
#define NH 8
#define HD 1024
#define QL 5
#define KKTOT 640   // DIM*QL
#define OCH 2048
#define MAXNNZ 384

typedef _Float16 hv2 __attribute__((ext_vector_type(2)));

#if defined(__has_builtin)
#  if __has_builtin(__builtin_amdgcn_fdot2)
#    define USE_FDOT2 1
#  endif
#endif
#ifndef USE_FDOT2
#  define USE_FDOT2 0
#endif

__device__ __forceinline__ hv2 u2h(unsigned u) {
    union { unsigned u; hv2 h; } c; c.u = u; return c.h;
}
__device__ __forceinline__ float dot2acc(unsigned a, unsigned b, float acc) {
#if USE_FDOT2
    return __builtin_amdgcn_fdot2(u2h(a), u2h(b), acc, false);
#else
    hv2 ha = u2h(a), hb = u2h(b);
    return acc + (float)ha[0] * (float)hb[0] + (float)ha[1] * (float)hb[1];
#endif
}

// ---------------- x (fp32) -> x16 (fp16)
__global__ void k_cvt_x(const float4* __restrict__ src, ushort4* __restrict__ dst, int n4) {
    int i = blockIdx.x * 256 + threadIdx.x;
    if (i >= n4) return;
    float4 v = src[i];
    ushort4 o;
    o.x = __half_as_ushort(__float2half(v.x));
    o.y = __half_as_ushort(__float2half(v.y));
    o.z = __half_as_ushort(__float2half(v.z));
    o.w = __half_as_ushort(__float2half(v.w));
    dst[i] = o;
}

// ---------------- w_qk (O,I,T) -> paired fp16: wtp[(p*QL+t)*OCH + o] = {w[o,2p,t], w[o,2p+1,t]}
__global__ void k_wqk_pair(const float* __restrict__ w, unsigned* __restrict__ wtp) {
    int j = blockIdx.x * 256 + threadIdx.x;   // 320*2048
    if (j >= (KKTOT / 2) * OCH) return;
    int o = j & 2047;
    int pt = j >> 11;            // p*5 + t
    int p = pt / QL, t = pt % QL;
    float a = w[(size_t)o * KKTOT + (2 * p) * QL + t];
    float b = w[(size_t)o * KKTOT + (2 * p + 1) * QL + t];
    unsigned lo = __half_as_ushort(__float2half(a));
    unsigned hi = __half_as_ushort(__float2half(b));
    wtp[j] = lo | (hi << 16);
}

// ---------------- w_v (128,1024) -> paired fp16: wvp[p*HD + c] = {wv[2p,c], wv[2p+1,c]}
__global__ void k_wv_pair(const float* __restrict__ wv, unsigned* __restrict__ wvp) {
    int j = blockIdx.x * 256 + threadIdx.x;   // 64*1024
    if (j >= (DIM / 2) * HD) return;
    int c = j & 1023;
    int p = j >> 10;
    float a = wv[(size_t)(2 * p) * HD + c];
    float b = wv[(size_t)(2 * p + 1) * HD + c];
    unsigned lo = __half_as_ushort(__float2half(a));
    unsigned hi = __half_as_ushort(__float2half(b));
    wvp[j] = lo | (hi << 16);
}

// ---------------- compact mask rows to CSR (deterministic ballot compaction)
__global__ void k_mask_csr(const float* __restrict__ mask, unsigned* __restrict__ cnt,
                           unsigned* __restrict__ idx) {
    __shared__ unsigned s_base;
    __shared__ unsigned s_wcnt[4];
    int r = blockIdx.x;
    int tid = threadIdx.x;
    int lane = tid & 63;
    int w = tid >> 6;
    if (tid == 0) s_base = 0;
    __syncthreads();
    for (int c0 = 0; c0 < S_LEN; c0 += 256) {
        int c = c0 + tid;
        bool act = mask[(size_t)r * S_LEN + c] > 0.5f;
        unsigned long long bal = __ballot(act);
        if (lane == 0) s_wcnt[w] = (unsigned)__popcll(bal);
        __syncthreads();
        unsigned off = s_base;
        for (int i = 0; i < w; i++) off += s_wcnt[i];
        off += (unsigned)__popcll(bal & ((1ull << lane) - 1ull));
        if (act && off < MAXNNZ) idx[r * MAXNNZ + off] = (unsigned)c;
        __syncthreads();
        if (tid == 0) s_base += s_wcnt[0] + s_wcnt[1] + s_wcnt[2] + s_wcnt[3];
        __syncthreads();
    }
    if (tid == 0) cnt[r] = (s_base < MAXNNZ) ? s_base : MAXNNZ;
}

// ---------------- value = x @ w_v + b_v, fp16 in / fp32 acc / fp16 out
// grid (BATCH*S/16, 4), block 256
__global__ void k_value16(const unsigned* __restrict__ x16u, const unsigned* __restrict__ wvp,
                          const float* __restrict__ bv, _Float16* __restrict__ val16) {
    __shared__ unsigned xs[16][64];   // 16 rows x 64 i-pairs
    int bs0 = blockIdx.x * 16;
    int c = blockIdx.y * 256 + threadIdx.x;
    for (int t = threadIdx.x; t < 16 * 64; t += 256)
        xs[t >> 6][t & 63] = x16u[(size_t)(bs0 + (t >> 6)) * 64 + (t & 63)];
    __syncthreads();
    float acc[16];
#pragma unroll
    for (int r = 0; r < 16; r++) acc[r] = 0.f;
    for (int p = 0; p < 64; p++) {
        unsigned w2 = wvp[(size_t)p * HD + c];
#pragma unroll
        for (int r = 0; r < 16; r++) acc[r] = dot2acc(xs[r][p], w2, acc[r]);
    }
    float b = bv[c];
#pragma unroll
    for (int r = 0; r < 16; r++)
        val16[(size_t)(bs0 + r) * HD + c] = (_Float16)(acc[r] + b);
}

// ---------------- qk conv, fp16 in / fp32 acc / fp16 out.  grid (BATCH*S/32, 8)
__global__ void k_qkconv16(const unsigned* __restrict__ x16u, const unsigned* __restrict__ wtp,
                           const float* __restrict__ bqk, _Float16* __restrict__ qk16) {
    __shared__ unsigned xs[36][64];   // 36 rows x 64 i-pairs
    int bs0 = blockIdx.x * 32;
    int b = bs0 >> 11;
    int s0 = bs0 & 2047;
    int o = blockIdx.y * 256 + threadIdx.x;
    for (int t = threadIdx.x; t < 36 * 64; t += 256) {
        int rr = t >> 6, p = t & 63;
        int s = s0 - 4 + rr;
        xs[rr][p] = (s >= 0) ? x16u[((size_t)b * S_LEN + s) * 64 + p] : 0u;
    }
    __syncthreads();
    float acc[32];
    float bias = bqk[o];
#pragma unroll
    for (int r = 0; r < 32; r++) acc[r] = bias;
    for (int p = 0; p < 64; p++) {
        unsigned xr[36];
#pragma unroll
        for (int rr = 0; rr < 36; rr++) xr[rr] = xs[rr][p];
#pragma unroll
        for (int t = 0; t < QL; t++) {
            unsigned w2 = wtp[(size_t)(p * QL + t) * OCH + o];
#pragma unroll
            for (int r = 0; r < 32; r++)
                acc[r] = dot2acc(xr[r + t], w2, acc[r]);
        }
    }
    for (int r = 0; r < 32; r++)
        qk16[((size_t)bs0 + r) * OCH + o] = (_Float16)acc[r];
}

// ---------------- sparse attention + entmax15, fp16 K/V gathers (r18, unchanged)
__global__ void __launch_bounds__(256) k_attn(const _Float16* __restrict__ qk16,
                                              const _Float16* __restrict__ val16,
                                              const unsigned* __restrict__ cnt,
                                              const unsigned* __restrict__ idxbuf,
                                              float* __restrict__ attout) {
    __shared__ float ssc[MAXNNZ];
    __shared__ unsigned sidx[MAXNNZ];
    __shared__ float pvs[16][128];
    __shared__ float red4[4];
    __shared__ float s_mx;
    int l = blockIdx.x;
    int bid = (l & 7) * 4096 + (l >> 3);   // XCD swizzle (32768 = 8 * 4096, bijective)
    int r = bid & (S_LEN - 1);
    int h = (bid >> 11) & (NH - 1);
    int b = bid >> 14;
    int tid = threadIdx.x;
    int lane = tid & 63;
    int wave = tid >> 6;
    int n = (int)cnt[r];
    const float scale = 0.08838834764831843f;  // 1/sqrt(128)

    for (int j = tid; j < n; j += 256) sidx[j] = idxbuf[r * MAXNNZ + j];
    __syncthreads();

    // ---- phase 1: scores; fp16 q in registers, fp16 K gathers, packed dot
    {
        int grp = tid >> 2;          // 0..63
        int ll  = tid & 3;           // lane within group
        const uint4* q16 = reinterpret_cast<const uint4*>(
                               qk16 + ((size_t)(b * S_LEN + r)) * OCH + h * 128);
        uint4 qreg[4];
#pragma unroll
        for (int i = 0; i < 4; i++) qreg[i] = q16[i * 4 + ll];
        const _Float16* kbase = qk16 + (size_t)b * S_LEN * OCH + HD + h * 128;
        for (int j = grp; j < n; j += 64) {
            const uint4* kp = reinterpret_cast<const uint4*>(kbase + (size_t)sidx[j] * OCH);
            float p = 0.f;
#pragma unroll
            for (int i = 0; i < 4; i++) {
                uint4 kv = kp[i * 4 + ll];
                const unsigned* ka = reinterpret_cast<const unsigned*>(&kv);
                const unsigned* qa = reinterpret_cast<const unsigned*>(&qreg[i]);
                p = dot2acc(qa[0], ka[0], p);
                p = dot2acc(qa[1], ka[1], p);
                p = dot2acc(qa[2], ka[2], p);
                p = dot2acc(qa[3], ka[3], p);
            }
            p += __shfl_xor(p, 1, 64);
            p += __shfl_xor(p, 2, 64);
            if (ll == 0) ssc[j] = p * scale;
        }
    }
    __syncthreads();

    // ---- phase 2a: block-wide max
    {
        float lmx = -3.0e38f;
        for (int j = tid; j < n; j += 256) lmx = fmaxf(lmx, ssc[j]);
#pragma unroll
        for (int off = 32; off >= 1; off >>= 1) lmx = fmaxf(lmx, __shfl_xor(lmx, off, 64));
        if (lane == 0) red4[wave] = lmx;
    }
    __syncthreads();
    if (tid == 0) s_mx = fmaxf(fmaxf(red4[0], red4[1]), fmaxf(red4[2], red4[3]));
    __syncthreads();
    float mx = s_mx;

    // ---- phase 2b: bisection on wave 0 (tree-summed, 26 iters)
    if (wave == 0) {
        float xl[6];
#pragma unroll
        for (int l2 = 0; l2 < 6; l2++) {
            int j = lane + 64 * l2;
            xl[l2] = (j < n) ? (ssc[j] - mx) * 0.5f : -1.0e30f;
        }
        float lo = -1.f, hi = 0.f;
        for (int it = 0; it < 26; it++) {
            float mid = 0.5f * (lo + hi);
            float d0 = fmaxf(xl[0] - mid, 0.f), d1 = fmaxf(xl[1] - mid, 0.f);
            float d2 = fmaxf(xl[2] - mid, 0.f), d3 = fmaxf(xl[3] - mid, 0.f);
            float d4 = fmaxf(xl[4] - mid, 0.f), d5 = fmaxf(xl[5] - mid, 0.f);
            float f = ((d0 * d0 + d1 * d1) + (d2 * d2 + d3 * d3)) + (d4 * d4 + d5 * d5);
#pragma unroll
            for (int off = 32; off >= 1; off >>= 1) f += __shfl_xor(f, off, 64);
            if (f > 1.f) lo = mid; else hi = mid;
        }
        float tau = 0.5f * (lo + hi);
#pragma unroll
        for (int l2 = 0; l2 < 6; l2++) {
            int j = lane + 64 * l2;
            if (j < n) {
                float d = fmaxf(xl[l2] - tau, 0.f);
                ssc[j] = d * d;
            }
        }
    }
    __syncthreads();

    // ---- phase 3: PV, fp16 V — 16 column-slots x 16 dim-groups (8 dims each)
    {
        int slot = tid >> 4;         // 0..15
        int dg   = tid & 15;         // 0..15, dims dg*8..dg*8+7
        const uint4* vbase = reinterpret_cast<const uint4*>(
                                 val16 + (size_t)b * S_LEN * HD + h * 128) + dg;
        float acc[8];
#pragma unroll
        for (int k = 0; k < 8; k++) acc[k] = 0.f;
        for (int j = slot; j < n; j += 16) {
            float w = ssc[j];
            uint4 vv = vbase[(size_t)sidx[j] << 7];     // row stride 1024 halves = 128 uint4
            const __half2* va = reinterpret_cast<const __half2*>(&vv);
#pragma unroll
            for (int k = 0; k < 4; k++) {
                float2 f = __half22float2(va[k]);
                acc[2 * k]     += w * f.x;
                acc[2 * k + 1] += w * f.y;
            }
        }
#pragma unroll
        for (int k = 0; k < 8; k++) pvs[slot][dg * 8 + k] = acc[k];
    }
    __syncthreads();
    if (tid < 128) {
        float a = 0.f;
#pragma unroll
        for (int s = 0; s < 16; s++) a += pvs[s][tid];
        attout[((size_t)(b * S_LEN + r)) * HD + h * 128 + tid] = a;
    }
}

// ---------------- out = attout @ w_proj + b_proj, store FLOAT32
// grid BATCH*S/16, block 256 (2-way split-K x 128 cols)
__global__ void k_proj(const float* __restrict__ ao, const float* __restrict__ wp,
                       const float* __restrict__ bp, float* __restrict__ out) {
    __shared__ float xs[2][16][128];
    int bs0 = blockIdx.x * 16;
    int tid = threadIdx.x;
    int dout = tid & 127;
    int kh = tid >> 7;
    float acc[16];
#pragma unroll
    for (int r = 0; r < 16; r++) acc[r] = 0.f;
    for (int cc = 0; cc < 4; cc++) {
        int kb = (kh + 2 * cc) * 128;
        __syncthreads();
        for (int t = dout; t < 16 * 128; t += 128)
            xs[kh][t >> 7][t & 127] = ao[(size_t)(bs0 + (t >> 7)) * HD + kb + (t & 127)];
        __syncthreads();
        for (int k = 0; k < 128; k += 4) {
            float w0 = wp[(kb + k + 0) * DIM + dout];
            float w1 = wp[(kb + k + 1) * DIM + dout];
            float w2 = wp[(kb + k + 2) * DIM + dout];
            float w3 = wp[(kb + k + 3) * DIM + dout];
#pragma unroll
            for (int r = 0; r < 16; r++) {
                float4 xv = *reinterpret_cast<const float4*>(&xs[kh][r][k]);
                acc[r] += xv.x * w0 + xv.y * w1 + xv.z * w2 + xv.w * w3;
            }
        }
    }
    __syncthreads();
#pragma unroll
    for (int r = 0; r < 16; r++) xs[kh][r][dout] = acc[r];
    __syncthreads();
    if (kh == 0) {
        float bb = bp[dout];
        for (int r = 0; r < 16; r++)
            out[(size_t)(bs0 + r) * DIM + dout] = xs[0][r][dout] + xs[1][r][dout] + bb;
    }
}

extern "C" void kernel_launch(void* const* d_in, const int* in_sizes, int n_in,
                              void* d_out, int out_size, void* d_ws, size_t ws_size,
                              hipStream_t stream) {
    const float* x      = (const float*)d_in[0];
    const float* mask   = (const float*)d_in[1];
    const float* w_qk   = (const float*)d_in[2];
    const float* b_qk   = (const float*)d_in[3];
    const float* w_v    = (const float*)d_in[4];
    const float* b_v    = (const float*)d_in[5];
    const float* w_proj = (const float*)d_in[6];
    const float* b_proj = (const float*)d_in[7];
    float* out = (float*)d_out;     // reference output dtype is FLOAT32

    char* ws = (char*)d_ws;
    _Float16*  x16   = (_Float16*)(ws + 0);         //  1,048,576 B
    _Float16*  qk16  = (_Float16*)(ws + 1048576);   // 16,777,216 B
    _Float16*  val16 = (_Float16*)(ws + 17825792);  //  8,388,608 B
    unsigned*  wtp   = (unsigned*)(ws + 26214400);  //  2,621,440 B
    unsigned*  wvp   = (unsigned*)(ws + 28835840);  //    262,144 B
    unsigned*  cnt   = (unsigned*)(ws + 29097984);  //      8,192 B
    unsigned*  idx   = (unsigned*)(ws + 29106176);  //  3,145,728 B
    float*     ao    = (float*)(ws + 32251904);     // 16,777,216 B -> end 49,029,120

    hipLaunchKernelGGL(k_cvt_x, dim3(BATCH * S_LEN * DIM / 4 / 256), dim3(256), 0, stream,
                       (const float4*)x, (ushort4*)x16, BATCH * S_LEN * DIM / 4);
    hipLaunchKernelGGL(k_wqk_pair, dim3((KKTOT / 2) * OCH / 256), dim3(256), 0, stream, w_qk, wtp);
    hipLaunchKernelGGL(k_wv_pair, dim3((DIM / 2) * HD / 256), dim3(256), 0, stream, w_v, wvp);
    hipLaunchKernelGGL(k_mask_csr, dim3(S_LEN), dim3(256), 0, stream, mask, cnt, idx);
    hipLaunchKernelGGL(k_value16, dim3((BATCH * S_LEN) / 16, 4), dim3(256), 0, stream,
                       (const unsigned*)x16, wvp, b_v, val16);
    hipLaunchKernelGGL(k_qkconv16, dim3((BATCH * S_LEN) / 32, 8), dim3(256), 0, stream,
                       (const unsigned*)x16, wtp, b_qk, qk16);
    hipLaunchKernelGGL(k_attn, dim3(BATCH * NH * S_LEN), dim3(256), 0, stream, qk16, val16, cnt, idx, ao);
    hipLaunchKernelGGL(k_proj, dim3((BATCH * S_LEN) / 16), dim3(256), 0, stream, ao, w_proj, b_proj, out);
}